// Round 3
// baseline (167.176 us; speedup 1.0000x reference)
//
#include <hip/hip_runtime.h>
#include <hip/hip_bf16.h>

#define B_     4
#define V_IN   12500
#define V_OUT  50000
#define C_IN   64
#define C_OUT  32
#define SPIRAL 9
#define K_NNZ  3
#define ROWS   (B_ * V_OUT)       // 200000
#define KDIM   (SPIRAL * C_IN)    // 576
#define KSTEPS (KDIM / 32)        // 18 (16x16x32 MFMA)
#define WFRAG_ELEMS (KSTEPS * 2 * 64 * 8)  // 18432 bf16 = 36864 B
#define HFRAG_ELEMS (SPIRAL * 2 * 64 * 8)  // 9216 bf16 = 18432 B (one K-half)

#define GROUPS_PER_B (V_OUT / 16) // 3125 16-row groups per batch (k1)
#define G1           2048         // k1 blocks (+1 W-prep); 256 per XCD
#define TILES_PER_B  782          // 781 full 64-row tiles + one 16-row tail (k2)
#define G2           1024         // k2 blocks; 128 per (b,ch) XCD; 4 blocks/CU
#define G3           2048         // combine blocks

typedef __attribute__((ext_vector_type(8))) short short8_t;      // 8 bf16 (4 VGPRs)
typedef __attribute__((ext_vector_type(4))) float floatx4;       // 4 fp32 acc
typedef __attribute__((ext_vector_type(4))) unsigned short u16x4;

__device__ __forceinline__ unsigned short f32_to_bf16(float f) {
    unsigned int u = __float_as_uint(f);
    unsigned int r = u + 0x7fffu + ((u >> 16) & 1u);   // round-to-nearest-even
    return (unsigned short)(r >> 16);
}

// Kernel 1: up[b,v,c] = sum_k x[b,up_idx[v,k],c]*up_val[v,k] -> bf16,
// stored as TWO channel planes: plane[ch][b][v][32], ch = c>>5.
// Each plane per batch = 50000*64B = 3.2 MB -> fits one XCD's 4 MB L2 in k2.
// (R2 verified: gemm FETCH_SIZE 170 MB -> 19.8 MB with this layout.)
// Block G1: rearrange weight (576x32 fp32) into MFMA fragment order (bf16):
//   w_frag[((kstep*2+ntile)*64+lane)*8+j] = W[kstep*32+(lane>>4)*8+j][ntile*16+(lane&15)]
__global__ __launch_bounds__(256) void upsample_kernel(
    const float* __restrict__ x,
    const int* __restrict__ up_idx,
    const float* __restrict__ up_val,
    const float* __restrict__ weight,
    unsigned short* __restrict__ up_planes,
    unsigned short* __restrict__ w_frag)
{
    int tid = threadIdx.x;
    if (blockIdx.x == G1) {
        for (int idx = tid; idx < WFRAG_ELEMS; idx += 256) {
            int j     = idx & 7;
            int lane  = (idx >> 3) & 63;
            int ntile = (idx >> 9) & 1;
            int kstep = idx >> 10;
            int k = kstep * 32 + (lane >> 4) * 8 + j;
            int n = ntile * 16 + (lane & 15);
            w_frag[idx] = f32_to_bf16(weight[k * C_OUT + n]);
        }
        return;
    }
    int xcd = blockIdx.x & 7;
    int b   = xcd >> 1;                     // batch owned by this XCD pair
    int h   = xcd & 1;
    int j   = blockIdx.x >> 3;              // [0, 256)
    int lane16 = tid & 15;                  // 4 channels each
    int sub    = tid >> 4;                  // row within 16-row group
    int half   = lane16 >> 3;               // channel plane (c>=32)
    int c8     = lane16 & 7;                // 4-short chunk within plane row

    const float* xb = x + (size_t)b * V_IN * C_IN;
    unsigned short* plane = up_planes
        + ((size_t)(half * B_ + b)) * V_OUT * 32 + (size_t)c8 * 4;

    for (int gl = h + 2 * j; gl < GROUPS_PER_B; gl += 512) {
        int v = gl * 16 + sub;              // local row within batch b
        const int*   ui = up_idx + v * K_NNZ;
        const float* uv = up_val + v * K_NNZ;
        float a0 = 0.f, a1 = 0.f, a2 = 0.f, a3 = 0.f;
#pragma unroll
        for (int k = 0; k < K_NNZ; k++) {
            int u = __builtin_nontemporal_load(ui + k);
            float val = __builtin_nontemporal_load(uv + k);
            const float4* xp = (const float4*)(xb + (size_t)u * C_IN) + lane16;
            float4 xv = *xp;
            a0 += val * xv.x; a1 += val * xv.y; a2 += val * xv.z; a3 += val * xv.w;
        }
        u16x4 o;
        o[0] = f32_to_bf16(a0); o[1] = f32_to_bf16(a1);
        o[2] = f32_to_bf16(a2); o[3] = f32_to_bf16(a3);
        __builtin_nontemporal_store(o, (u16x4*)(plane + (size_t)v * 32));
    }
}

// Kernel 2: partial GEMM over one K-half. XCD xcd = b*2+ch. R3 change:
// two tiles per iteration, ALL 18 gathers + 18 spiral indices issued before
// any MFMA, pinned live by a single asm statement (R2's per-fragment pins
// allowed the register allocator to squeeze to 36 VGPR and serialize the
// gathers -> 5% MfmaUtil, pure latency). One exposed L2 round-trip per
// 2-tile pair instead of ~9 per tile.
__global__ __launch_bounds__(256, 2) void gemm_half_kernel(
    const unsigned short* __restrict__ up_planes,
    const int* __restrict__ spiral,
    const unsigned short* __restrict__ w_frag,
    float* __restrict__ p0,
    float* __restrict__ out)
{
    __shared__ unsigned short w_lds[HFRAG_ELEMS];   // 18432 B

    int tid  = threadIdx.x;
    int wave = tid >> 6;
    int lane = tid & 63;
    int m    = lane & 15;
    int quad = lane >> 4;

    int xcd = blockIdx.x & 7;
    int b   = xcd >> 1;
    int ch  = xcd & 1;
    int j   = blockIdx.x >> 3;              // [0, 128)

    // Stage this half's 18 W fragments (ksteps 2s+ch) into LDS.
    for (int i = tid; i < HFRAG_ELEMS / 8; i += 256) {
        int fl = i >> 6;                    // local fragment 0..17
        int ln = i & 63;
        int s  = fl >> 1;
        int nt = fl & 1;
        int fg = (2 * s + ch) * 2 + nt;     // global fragment index
        ((short8_t*)w_lds)[i] = ((const short8_t*)w_frag)[fg * 64 + ln];
    }
    __syncthreads();

    const short8_t* wl = (const short8_t*)w_lds + lane;  // + f*64

    const unsigned short* upb = up_planes + ((size_t)(ch * B_ + b)) * V_OUT * 32;
    float* dst = (ch ? out : p0) + (size_t)b * V_OUT * C_OUT;

    for (int tl = j; tl < TILES_PER_B; tl += 256) {
        int tl2   = tl + 128;
        int haveB = tl2 < TILES_PER_B;      // block-uniform (j uniform)

        // ---- issue phase: all index loads, then all gathers, no MFMA ----
        int vrA = tl * 64 + wave * 16 + m;
        int vA  = vrA < V_OUT ? vrA : 0;
        const int* pA = spiral + vA * SPIRAL;
        int vrB = tl2 * 64 + wave * 16 + m;
        int vB  = (haveB && vrB < V_OUT) ? vrB : 0;
        const int* pB = spiral + vB * SPIRAL;

        int spvA[SPIRAL], spvB[SPIRAL];
#pragma unroll
        for (int s = 0; s < SPIRAL; s++) spvA[s] = __builtin_nontemporal_load(pA + s);
#pragma unroll
        for (int s = 0; s < SPIRAL; s++) spvB[s] = __builtin_nontemporal_load(pB + s);

        short8_t gA[SPIRAL], gB[SPIRAL];
#pragma unroll
        for (int s = 0; s < SPIRAL; s++)
            gA[s] = *(const short8_t*)(upb + (size_t)spvA[s] * 32 + quad * 8);
#pragma unroll
        for (int s = 0; s < SPIRAL; s++)
            gB[s] = *(const short8_t*)(upb + (size_t)spvB[s] * 32 + quad * 8);

        // Single pin: all 18 fragments must be resident before MFMA starts.
        asm volatile("" ::
            "v"(gA[0]), "v"(gA[1]), "v"(gA[2]), "v"(gA[3]), "v"(gA[4]),
            "v"(gA[5]), "v"(gA[6]), "v"(gA[7]), "v"(gA[8]),
            "v"(gB[0]), "v"(gB[1]), "v"(gB[2]), "v"(gB[3]), "v"(gB[4]),
            "v"(gB[5]), "v"(gB[6]), "v"(gB[7]), "v"(gB[8]));

        // ---- tile A: MFMA + store ----
        {
            floatx4 acc0 = {0.f, 0.f, 0.f, 0.f};
            floatx4 acc1 = {0.f, 0.f, 0.f, 0.f};
#pragma unroll
            for (int s = 0; s < SPIRAL; s++) {
                short8_t wA = wl[(2 * s + 0) * 64];
                short8_t wB = wl[(2 * s + 1) * 64];
                acc0 = __builtin_amdgcn_mfma_f32_16x16x32_bf16(wA, gA[s], acc0, 0, 0, 0);
                acc1 = __builtin_amdgcn_mfma_f32_16x16x32_bf16(wB, gA[s], acc1, 0, 0, 0);
            }
            if (vrA < V_OUT) {
                float* op = dst + (size_t)vrA * C_OUT;
                __builtin_nontemporal_store(acc0, (floatx4*)(op + quad * 4));
                __builtin_nontemporal_store(acc1, (floatx4*)(op + 16 + quad * 4));
            }
        }

        // ---- tile B: MFMA + store ----
        if (haveB) {
            floatx4 acc0 = {0.f, 0.f, 0.f, 0.f};
            floatx4 acc1 = {0.f, 0.f, 0.f, 0.f};
#pragma unroll
            for (int s = 0; s < SPIRAL; s++) {
                short8_t wA = wl[(2 * s + 0) * 64];
                short8_t wB = wl[(2 * s + 1) * 64];
                acc0 = __builtin_amdgcn_mfma_f32_16x16x32_bf16(wA, gB[s], acc0, 0, 0, 0);
                acc1 = __builtin_amdgcn_mfma_f32_16x16x32_bf16(wB, gB[s], acc1, 0, 0, 0);
            }
            if (vrB < V_OUT) {
                float* op = dst + (size_t)vrB * C_OUT;
                __builtin_nontemporal_store(acc0, (floatx4*)(op + quad * 4));
                __builtin_nontemporal_store(acc1, (floatx4*)(op + 16 + quad * 4));
            }
        }
    }
}

// Kernel 3: out = relu(out + p0 + bias). Pure streaming, nontemporal.
// R2: ran at ~5.9 TB/s effective — near roofline for its 77 MB.
__global__ __launch_bounds__(256) void combine_kernel(
    const float* __restrict__ p0,
    const float* __restrict__ bias,
    float* __restrict__ out)
{
    const size_t total = (size_t)ROWS * (C_OUT / 4);   // 1.6M float4 units
    size_t idx = (size_t)blockIdx.x * 256 + threadIdx.x;
    size_t stride = (size_t)G3 * 256;
    for (size_t i = idx; i < total; i += stride) {
        floatx4 a = __builtin_nontemporal_load((const floatx4*)p0 + i);
        floatx4 c = __builtin_nontemporal_load((const floatx4*)out + i);
        floatx4 bb = *((const floatx4*)bias + (i & 7));
        floatx4 r = a + c + bb;
        r[0] = fmaxf(r[0], 0.f); r[1] = fmaxf(r[1], 0.f);
        r[2] = fmaxf(r[2], 0.f); r[3] = fmaxf(r[3], 0.f);
        __builtin_nontemporal_store(r, (floatx4*)out + i);
    }
}

extern "C" void kernel_launch(void* const* d_in, const int* in_sizes, int n_in,
                              void* d_out, int out_size, void* d_ws, size_t ws_size,
                              hipStream_t stream) {
    const float* x      = (const float*)d_in[0];
    const int*   spiral = (const int*)d_in[1];
    const int*   up_idx = (const int*)d_in[2];
    const float* up_val = (const float*)d_in[3];
    const float* weight = (const float*)d_in[4];
    const float* bias   = (const float*)d_in[5];
    float* out = (float*)d_out;

    // ws layout: planes (25.6 MB) | w_frag (36 KB) | p0 (25.6 MB) = 51.3 MB
    unsigned short* up_ws  = (unsigned short*)d_ws;
    unsigned short* w_frag = up_ws + (size_t)2 * B_ * V_OUT * 32;
    float* p0 = (float*)(w_frag + WFRAG_ELEMS);

    upsample_kernel<<<G1 + 1, 256, 0, stream>>>(x, up_idx, up_val, weight, up_ws, w_frag);
    gemm_half_kernel<<<G2, 256, 0, stream>>>(up_ws, spiral, w_frag, p0, out);
    combine_kernel<<<G3, 256, 0, stream>>>(p0, bias, out);
}

// Round 5
// 150.513 us; speedup vs baseline: 1.1107x; 1.1107x over previous
//
#include <hip/hip_runtime.h>
#include <hip/hip_bf16.h>

#define B_     4
#define V_IN   12500
#define V_OUT  50000
#define C_IN   64
#define C_OUT  32
#define SPIRAL 9
#define K_NNZ  3
#define ROWS   (B_ * V_OUT)       // 200000
#define KDIM   (SPIRAL * C_IN)    // 576
#define KSTEPS (KDIM / 32)        // 18 (16x16x32 MFMA)
#define WFRAG_ELEMS (KSTEPS * 2 * 64 * 8)  // 18432 bf16 = 36864 B

#define GROUPS_PER_B (V_OUT / 16) // 3125 16-row groups per batch (k1)
#define G1           2048         // k1 blocks (+1 W-prep); 256 per XCD
#define TILES_PER_B  782          // 781 full 64-row tiles + one 16-row tail (k2)
#define G2           768          // k2: 96 blocks per (b,ch) XCD; 3 blocks/CU
#define TSTEP        96           // tiles stride = blocks per partition
#define G3           2048         // combine blocks

typedef __attribute__((ext_vector_type(8))) short short8_t;      // 8 bf16 (4 VGPRs)
typedef __attribute__((ext_vector_type(4))) float floatx4;       // 4 fp32 acc
typedef __attribute__((ext_vector_type(4))) unsigned short u16x4;

__device__ __forceinline__ unsigned short f32_to_bf16(float f) {
    unsigned int u = __float_as_uint(f);
    unsigned int r = u + 0x7fffu + ((u >> 16) & 1u);   // round-to-nearest-even
    return (unsigned short)(r >> 16);
}

// Async global->LDS, 16B per lane. LDS dest = base + lane*16 (linear, HW rule).
__device__ __forceinline__ void glds16(const void* g, void* l) {
    __builtin_amdgcn_global_load_lds(
        (const __attribute__((address_space(1))) unsigned int*)g,
        (__attribute__((address_space(3))) unsigned int*)l, 16, 0, 0);
}

// Kernel 1: up[b,v,c] = sum_k x[b,up_idx[v,k],c]*up_val[v,k] -> bf16,
// stored as TWO channel planes: plane[ch][b][v][32], ch = c>>5.
// Each plane per batch = 50000*64B = 3.2 MB -> fits one XCD's 4 MB L2 in k2.
// (R2 verified: gemm FETCH_SIZE 170 MB -> 19.8 MB with this layout.)
// Block G1: rearrange weight (576x32 fp32) into MFMA fragment order (bf16):
//   w_frag[((kstep*2+ntile)*64+lane)*8+j] = W[kstep*32+(lane>>4)*8+j][ntile*16+(lane&15)]
__global__ __launch_bounds__(256) void upsample_kernel(
    const float* __restrict__ x,
    const int* __restrict__ up_idx,
    const float* __restrict__ up_val,
    const float* __restrict__ weight,
    unsigned short* __restrict__ up_planes,
    unsigned short* __restrict__ w_frag)
{
    int tid = threadIdx.x;
    if (blockIdx.x == G1) {
        for (int idx = tid; idx < WFRAG_ELEMS; idx += 256) {
            int j     = idx & 7;
            int lane  = (idx >> 3) & 63;
            int ntile = (idx >> 9) & 1;
            int kstep = idx >> 10;
            int k = kstep * 32 + (lane >> 4) * 8 + j;
            int n = ntile * 16 + (lane & 15);
            w_frag[idx] = f32_to_bf16(weight[k * C_OUT + n]);
        }
        return;
    }
    int xcd = blockIdx.x & 7;
    int b   = xcd >> 1;                     // batch owned by this XCD pair
    int h   = xcd & 1;
    int j   = blockIdx.x >> 3;              // [0, 256)
    int lane16 = tid & 15;                  // 4 channels each
    int sub    = tid >> 4;                  // row within 16-row group
    int half   = lane16 >> 3;               // channel plane (c>=32)
    int c8     = lane16 & 7;                // 4-short chunk within plane row

    const float* xb = x + (size_t)b * V_IN * C_IN;
    unsigned short* plane = up_planes
        + ((size_t)(half * B_ + b)) * V_OUT * 32 + (size_t)c8 * 4;

    for (int gl = h + 2 * j; gl < GROUPS_PER_B; gl += 512) {
        int v = gl * 16 + sub;              // local row within batch b
        const int*   ui = up_idx + v * K_NNZ;
        const float* uv = up_val + v * K_NNZ;
        float a0 = 0.f, a1 = 0.f, a2 = 0.f, a3 = 0.f;
#pragma unroll
        for (int k = 0; k < K_NNZ; k++) {
            int u = __builtin_nontemporal_load(ui + k);
            float val = __builtin_nontemporal_load(uv + k);
            const float4* xp = (const float4*)(xb + (size_t)u * C_IN) + lane16;
            float4 xv = *xp;
            a0 += val * xv.x; a1 += val * xv.y; a2 += val * xv.z; a3 += val * xv.w;
        }
        u16x4 o;
        o[0] = f32_to_bf16(a0); o[1] = f32_to_bf16(a1);
        o[2] = f32_to_bf16(a2); o[3] = f32_to_bf16(a3);
        __builtin_nontemporal_store(o, (u16x4*)(plane + (size_t)v * 32));
    }
}

// Kernel 2: partial GEMM over one K-half. XCD xcd = b*2+ch.
// TRANSPOSED gather via global_load_lds (R4 design, resubmitted after
// infra failure):
//  - lane l = (r=l>>2, q=l&3): 4-lane cluster reads one contiguous 64B row
//    (same 128B line -> TCP coalesces; ~4x fewer L2 transactions than the
//    old one-row-per-16-lanes pattern that measured as request-rate-bound
//    53-77us across four different k2 structures).
//  - global_load_lds: zero dest VGPRs -> nothing for the register allocator
//    to squeeze (R1/R2/R3 all lost to VGPR squeezing of preloaded frags).
//  - sector swizzle on the GLOBAL side (q^((r>>1)&3)) + matching ds_read
//    offset -> 2-way LDS bank conflicts max (free per m136).
//  - per-wave private slot buffers: no __syncthreads in the loop.
//  - W fragments (18 x 16B = 72 VGPR) register-resident.
__global__ __launch_bounds__(256, 3) void gemm_half_kernel(
    const unsigned short* __restrict__ up_planes,
    const int* __restrict__ spiral,
    const unsigned short* __restrict__ w_frag,
    float* __restrict__ p0,
    float* __restrict__ out)
{
    __shared__ unsigned short gbuf[4 * SPIRAL * 512];   // 4 waves * 9 KB

    int tid  = threadIdx.x;
    int wave = tid >> 6;
    int lane = tid & 63;
    int m    = lane & 15;
    int quad = lane >> 4;
    int r    = lane >> 2;          // gather row within 16-row wave tile
    int q    = lane & 3;           // gather sector lane
    int swz  = q ^ ((r >> 1) & 3); // sector actually fetched by this lane
    int fm   = (m >> 1) & 3;       // read-side swizzle for row m

    int xcd = blockIdx.x & 7;
    int b   = xcd >> 1;
    int ch  = xcd & 1;
    int j   = blockIdx.x >> 3;              // [0, TSTEP)

    // W fragments for this half -> registers (loop-invariant, 72 VGPR).
    short8_t w[2 * SPIRAL];
#pragma unroll
    for (int f = 0; f < 2 * SPIRAL; f++) {
        int s  = f >> 1;
        int nt = f & 1;
        w[f] = *(const short8_t*)(w_frag + (((size_t)(2 * s + ch) * 2 + nt) * 64 + lane) * 8);
    }

    const unsigned short* upb = up_planes + ((size_t)(ch * B_ + b)) * V_OUT * 32;
    float* dst = (ch ? out : p0) + (size_t)b * V_OUT * C_OUT;
    char* mybuf = (char*)(gbuf + (size_t)wave * SPIRAL * 512);

    // Prologue: indices for first tile (each lane loads its own row-r's 9).
    int spv[SPIRAL];
    {
        int v0 = j * 64 + wave * 16 + r;
        int v  = v0 < V_OUT ? v0 : 0;
        const int* p = spiral + (size_t)v * SPIRAL;
#pragma unroll
        for (int s = 0; s < SPIRAL; s++) spv[s] = p[s];
    }

    for (int tl = j; tl < TILES_PER_B; tl += TSTEP) {
        // Issue 9 transposed gathers (no dest regs; LDS dest lane-linear).
#pragma unroll
        for (int s = 0; s < SPIRAL; s++) {
            const void* ga = (const char*)upb + (size_t)spv[s] * 64 + swz * 16;
            glds16(ga, mybuf + s * 1024);
        }

        // Prefetch next tile's indices (independent; overlaps gather latency).
        int tln = tl + TSTEP;
        int vn  = tln * 64 + wave * 16 + r;
        vn = (vn < V_OUT) ? vn : 0;
        const int* pn = spiral + (size_t)vn * SPIRAL;
        int nspv[SPIRAL];
#pragma unroll
        for (int s = 0; s < SPIRAL; s++) nspv[s] = pn[s];

        asm volatile("s_waitcnt vmcnt(0)" ::: "memory");
        __builtin_amdgcn_sched_barrier(0);   // keep ds_reads below the wait

        floatx4 acc0 = {0.f, 0.f, 0.f, 0.f};
        floatx4 acc1 = {0.f, 0.f, 0.f, 0.f};
#pragma unroll
        for (int s = 0; s < SPIRAL; s++) {
            short8_t g = *(const short8_t*)(mybuf + s * 1024 + m * 64 + ((quad ^ fm) * 16));
            acc0 = __builtin_amdgcn_mfma_f32_16x16x32_bf16(w[2 * s + 0], g, acc0, 0, 0, 0);
            acc1 = __builtin_amdgcn_mfma_f32_16x16x32_bf16(w[2 * s + 1], g, acc1, 0, 0, 0);
        }

        int vr = tl * 64 + wave * 16 + m;
        if (vr < V_OUT) {
            float* op = dst + (size_t)vr * C_OUT;
            __builtin_nontemporal_store(acc0, (floatx4*)(op + quad * 4));
            __builtin_nontemporal_store(acc1, (floatx4*)(op + 16 + quad * 4));
        }

#pragma unroll
        for (int s = 0; s < SPIRAL; s++) spv[s] = nspv[s];
    }
}

// Kernel 3: out = relu(out + p0 + bias). Pure streaming, nontemporal.
__global__ __launch_bounds__(256) void combine_kernel(
    const float* __restrict__ p0,
    const float* __restrict__ bias,
    float* __restrict__ out)
{
    const size_t total = (size_t)ROWS * (C_OUT / 4);   // 1.6M float4 units
    size_t idx = (size_t)blockIdx.x * 256 + threadIdx.x;
    size_t stride = (size_t)G3 * 256;
    for (size_t i = idx; i < total; i += stride) {
        floatx4 a = __builtin_nontemporal_load((const floatx4*)p0 + i);
        floatx4 c = __builtin_nontemporal_load((const floatx4*)out + i);
        floatx4 bb = *((const floatx4*)bias + (i & 7));
        floatx4 r = a + c + bb;
        r[0] = fmaxf(r[0], 0.f); r[1] = fmaxf(r[1], 0.f);
        r[2] = fmaxf(r[2], 0.f); r[3] = fmaxf(r[3], 0.f);
        __builtin_nontemporal_store(r, (floatx4*)out + i);
    }
}

extern "C" void kernel_launch(void* const* d_in, const int* in_sizes, int n_in,
                              void* d_out, int out_size, void* d_ws, size_t ws_size,
                              hipStream_t stream) {
    const float* x      = (const float*)d_in[0];
    const int*   spiral = (const int*)d_in[1];
    const int*   up_idx = (const int*)d_in[2];
    const float* up_val = (const float*)d_in[3];
    const float* weight = (const float*)d_in[4];
    const float* bias   = (const float*)d_in[5];
    float* out = (float*)d_out;

    // ws layout: planes (25.6 MB) | w_frag (36 KB) | p0 (25.6 MB) = 51.3 MB
    unsigned short* up_ws  = (unsigned short*)d_ws;
    unsigned short* w_frag = up_ws + (size_t)2 * B_ * V_OUT * 32;
    float* p0 = (float*)(w_frag + WFRAG_ELEMS);

    upsample_kernel<<<G1 + 1, 256, 0, stream>>>(x, up_idx, up_val, weight, up_ws, w_frag);
    gemm_half_kernel<<<G2, 256, 0, stream>>>(up_ws, spiral, w_frag, p0, out);
    combine_kernel<<<G3, 256, 0, stream>>>(p0, bias, out);
}